// Round 21
// baseline (136.581 us; speedup 1.0000x reference)
//
#include <hip/hip_runtime.h>
#include <math.h>

// FCM mutual-kNN attention mixing. N=8192, D=256, K=16.
//   K1 pack:   feats -> fbp fragment order + fp64 row sqnorms + zero cnt_g
//   K1b stats: deterministic reduction of sq -> mu/var
//   K2 gemm:   32 rows/block, A fully in VGPRs (loaded once, coalesced),
//              B coalesced fragment stream depth-2 slot-reuse; NO LDS reads,
//              NO barriers in main loop; threshold select -> packed LDS cbuf.
//   K2b fallback: parallel scan for bad rows + full-rescan repair (expected 0)
//   K3 refine: top-24 by packed key -> fp64 dot (np formula) -> exact top-17
//   K4 out:    mutual mask + sparse softmax + mix + normalize
#define NPTS 8192
#define DIM  256
#define NSLOT 17
#define CAP  256
#define LCAP 48
#define RSEL 24
#define ZTH  (-2.45f)
typedef unsigned int uint;
typedef unsigned short ushort;
typedef unsigned long long ull;
typedef __attribute__((ext_vector_type(8))) short bf16x8;
typedef __attribute__((ext_vector_type(4))) float f32x4;

__device__ __forceinline__ ushort f2bf(float f) {
    uint x = __float_as_uint(f);
    return (ushort)((x + 0x7fffu + ((x >> 16) & 1u)) >> 16);
}

// ---------------- K1: pack feats -> fragment order + fp64 sqnorms + cnt_g=0 ----------------
__global__ void pack_kernel(const float* __restrict__ feats, ushort* __restrict__ fbp,
                            float* __restrict__ sq, double* __restrict__ sqd,
                            int* __restrict__ cnt_g) {
    const int cb = (blockIdx.x * 256 + threadIdx.x) >> 6;   // global wave id
    const int l  = threadIdx.x & 63;
    const int l15 = l & 15, lg = l >> 4;
    const float* src = feats + (size_t)(cb * 16 + l15) * DIM + lg * 8;
    ushort* dst = fbp + (size_t)cb * 4096 + l * 8;
    double pd = 0.0;
#pragma unroll
    for (int kb = 0; kb < 8; ++kb) {
        const float4 v0 = *reinterpret_cast<const float4*>(src + kb * 32);
        const float4 v1 = *reinterpret_cast<const float4*>(src + kb * 32 + 4);
        pd += (double)v0.x * v0.x + (double)v0.y * v0.y +
              (double)v0.z * v0.z + (double)v0.w * v0.w;
        pd += (double)v1.x * v1.x + (double)v1.y * v1.y +
              (double)v1.z * v1.z + (double)v1.w * v1.w;
        bf16x8 bv;
        bv[0] = (short)f2bf(v0.x); bv[1] = (short)f2bf(v0.y);
        bv[2] = (short)f2bf(v0.z); bv[3] = (short)f2bf(v0.w);
        bv[4] = (short)f2bf(v1.x); bv[5] = (short)f2bf(v1.y);
        bv[6] = (short)f2bf(v1.z); bv[7] = (short)f2bf(v1.w);
        *reinterpret_cast<bf16x8*>(dst + kb * 512) = bv;
    }
    pd += __shfl_xor(pd, 16, 64);
    pd += __shfl_xor(pd, 32, 64);
    if (lg == 0) {
        const int row = cb * 16 + l15;
        sq[row] = (float)pd; sqd[row] = pd; cnt_g[row] = 0;
    }
}

// ---------------- K1b: deterministic stats (mu, var) ----------------
__global__ void stats_kernel(const float* __restrict__ sq, float* __restrict__ musig) {
    __shared__ double s0s[16], s1s[16];
    const int t = threadIdx.x, lane = t & 63, w = t >> 6;
    double s0 = 0.0, s1 = 0.0;
    for (int r = t; r < NPTS; r += 1024) {
        const double v = (double)sq[r];
        s0 += v; s1 += v * v;
    }
#pragma unroll
    for (int off = 32; off > 0; off >>= 1) {
        s0 += __shfl_down(s0, off, 64);
        s1 += __shfl_down(s1, off, 64);
    }
    if (lane == 0) { s0s[w] = s0; s1s[w] = s1; }
    __syncthreads();
    if (t == 0) {
        double a0 = 0.0, a1 = 0.0;
#pragma unroll
        for (int q = 0; q < 16; ++q) { a0 += s0s[q]; a1 += s1s[q]; }
        const double mu = a0 / NPTS;
        const double var = a1 / NPTS - mu * mu;
        musig[0] = (float)mu;
        musig[1] = (float)fmax(var, 1.0);
    }
}

// ---------------- K2: reg-resident MFMA GEMM + fused threshold select ----------------
// 512 thr = 8 waves. Block: 32 rows x one 2048-col quarter (quarter pinned/XCD).
// A fully in registers (a[2][8], loaded once, coalesced from fbp). Wave w covers
// cols w*32..+31 of each 256-col tile; B depth-2 slot-reuse register ping-pong.
// Main loop: NO LDS accesses, NO barriers.
__global__ __launch_bounds__(512, 2) void gemm_select_kernel(
    const ushort* __restrict__ fbp, const float* __restrict__ sq,
    const float* __restrict__ musig, int* __restrict__ cand, int* __restrict__ cnt_g) {
    __shared__ int    cbuf[32][LCAP];    // 6 KB packed (keyq<<13)|idx
    __shared__ float  Ts[32], sqi_s[32];
    __shared__ int    cnt[32];
    __shared__ int    base_s[32], n_s[32];

    const int tid = threadIdx.x;
    const int w   = tid >> 6;
    const int l   = tid & 63;
    const int l15 = l & 15, lg = l >> 4;
    const int rowblk = (blockIdx.x >> 3) * 2 + (blockIdx.x & 1);   // 0..255
    const int row0   = rowblk * 32;
    const int Jbase  = ((blockIdx.x & 7) >> 1) * 2048;

    if (tid < 32) {
        const float mu  = musig[0];
        const float var = musig[1];
        const float qi  = sq[row0 + tid];
        sqi_s[tid] = qi;
        Ts[tid]    = qi + mu + ZTH * sqrtf(var + 4.f * qi);
        cnt[tid]   = 0;
    }

    // A resident: a[mf][ks] = fragment (colblk (row0>>4)+mf, slot ks), coalesced
    bf16x8 a[2][8];
#pragma unroll
    for (int mf = 0; mf < 2; ++mf) {
        const ushort* ap = fbp + (size_t)((row0 >> 4) + mf) * 4096 + l * 8;
#pragma unroll
        for (int ks = 0; ks < 8; ++ks)
            a[mf][ks] = *reinterpret_cast<const bf16x8*>(ap + ks * 512);
    }
    __syncthreads();                     // Ts/cnt visible; only barrier pre-merge

    const int gcol = w * 32;
    const ushort* bp = fbp + (size_t)((Jbase >> 4) + w * 2) * 4096 + l * 8;

    bf16x8 bb[2][2];
#pragma unroll
    for (int cf = 0; cf < 2; ++cf) {
        bb[0][cf] = *reinterpret_cast<const bf16x8*>(bp + cf * 4096);          // step 0
        bb[1][cf] = *reinterpret_cast<const bf16x8*>(bp + cf * 4096 + 512);    // step 1
    }

    for (int tile = 0; tile < 8; ++tile) {
        f32x4 acc[2][2];
#pragma unroll
        for (int mf = 0; mf < 2; ++mf) {
            acc[mf][0] = (f32x4){0.f, 0.f, 0.f, 0.f};
            acc[mf][1] = (f32x4){0.f, 0.f, 0.f, 0.f};
        }
#pragma unroll
        for (int ks = 0; ks < 8; ++ks) {
            const int cur = ks & 1;
#pragma unroll
            for (int mf = 0; mf < 2; ++mf) {
                acc[mf][0] = __builtin_amdgcn_mfma_f32_16x16x32_bf16(a[mf][ks], bb[cur][0], acc[mf][0], 0, 0, 0);
                acc[mf][1] = __builtin_amdgcn_mfma_f32_16x16x32_bf16(a[mf][ks], bb[cur][1], acc[mf][1], 0, 0, 0);
            }
            // depth-2 prefetch: step+2 into the slot just consumed
            if (tile < 7 || ks < 6) {
                const int ntile = (ks >= 6) ? tile + 1 : tile;
                const int nks   = (ks + 2) & 7;
#pragma unroll
                for (int cf = 0; cf < 2; ++cf)
                    bb[cur][cf] = *reinterpret_cast<const bf16x8*>(
                        bp + (size_t)ntile * 65536 + cf * 4096 + nks * 512);
            }
        }
        // ---- per-tile epilogue: threshold select, packed into LDS cbuf ----
        const int Jt = Jbase + tile * 256;
        float sqc[2];
#pragma unroll
        for (int cf = 0; cf < 2; ++cf) sqc[cf] = sq[Jt + gcol + cf * 16 + l15];
#pragma unroll
        for (int mf = 0; mf < 2; ++mf)
#pragma unroll
            for (int cf = 0; cf < 2; ++cf)
#pragma unroll
                for (int r = 0; r < 4; ++r) {
                    const int row = mf * 16 + lg * 4 + r;
                    const float tt = Ts[row];
                    const float key = sqi_s[row] + sqc[cf] - 2.f * acc[mf][cf][r];
                    if (key < tt) {
                        const int kq2 = min((int)((tt - key) * 4096.f), 524287);
                        const uint val = ((uint)max(kq2, 0) << 13) |
                                         (uint)(Jt + gcol + cf * 16 + l15);
                        const int pos = atomicAdd(&cnt[row], 1);
                        if (pos < LCAP) cbuf[row][pos] = (int)val;
                    }
                }
    }
    __syncthreads();
    if (tid < 32) {
        const int local = cnt[tid];
        const int n = min(local, LCAP);
        const int add = (local > LCAP) ? (n + (1 << 20)) : n;   // poison on overflow
        base_s[tid] = atomicAdd(&cnt_g[row0 + tid], add);
        n_s[tid] = n;
    }
    __syncthreads();
    for (int s = tid; s < 32 * LCAP; s += 512) {
        const int r = s / LCAP, k2 = s - r * LCAP;
        if (k2 < n_s[r]) {
            const int b = base_s[r] + k2;
            if (b < CAP) cand[(size_t)(row0 + r) * CAP + b] = cbuf[r][k2];
        }
    }
}

// ---------------- K2b: parallel bad-row scan + repair (expected none) ----------------
__global__ void fallback_kernel(const float* __restrict__ feats, const float* __restrict__ sq,
                                int* __restrict__ cand, int* __restrict__ cnt_g) {
    __shared__ float fi_s[DIM];
    __shared__ float keys[NPTS];
    __shared__ float rkey[4];
    __shared__ int   rid[4];
    __shared__ int   badlist[256];
    __shared__ int   nbad_s;
    const int t = threadIdx.x;
    if (t == 0) nbad_s = 0;
    __syncthreads();
    {
        const int myrow = blockIdx.x * 256 + t;
        const int v = cnt_g[myrow];
        if (v < NSLOT || v > CAP) badlist[atomicAdd(&nbad_s, 1)] = myrow;
    }
    __syncthreads();
    const int nb = nbad_s;
    for (int bi = 0; bi < nb; ++bi) {
        const int row = badlist[bi];
        fi_s[t] = feats[(size_t)row * DIM + t];
        __syncthreads();
        const float sqi = sq[row];
        for (int p = 0; p < NPTS / 256; ++p) {
            const int jj = p * 256 + t;
            const float* fj = feats + (size_t)jj * DIM;
            float d = 0.f;
            for (int dq = 0; dq < DIM / 4; ++dq) {
                const float4 b4 = *reinterpret_cast<const float4*>(fj + dq * 4);
                const float4 a4 = *reinterpret_cast<const float4*>(&fi_s[dq * 4]);
                d = fmaf(a4.x, b4.x, fmaf(a4.y, b4.y, fmaf(a4.z, b4.z, fmaf(a4.w, b4.w, d))));
            }
            keys[jj] = sqi + sq[jj] - 2.f * d;
        }
        __syncthreads();
        for (int r = 0; r < 64; ++r) {
            float bk = INFINITY; int bj = 0x7fffffff;
            for (int p = 0; p < NPTS / 256; ++p) {
                const int jj = p * 256 + t;
                const float kv = keys[jj];
                if (kv < bk || (kv == bk && jj < bj)) { bk = kv; bj = jj; }
            }
#pragma unroll
            for (int off = 1; off <= 32; off <<= 1) {
                const float ok = __shfl_xor(bk, off, 64);
                const int   oj = __shfl_xor(bj, off, 64);
                if (ok < bk || (ok == bk && oj < bj)) { bk = ok; bj = oj; }
            }
            if ((t & 63) == 0) { rkey[t >> 6] = bk; rid[t >> 6] = bj; }
            __syncthreads();
            float fk = rkey[0]; int fj2 = rid[0];
#pragma unroll
            for (int q = 1; q < 4; ++q)
                if (rkey[q] < fk || (rkey[q] == fk && rid[q] < fj2)) { fk = rkey[q]; fj2 = rid[q]; }
            if (t == 0) {   // rank-ordered packed key (idx in low 13 bits)
                cand[(size_t)row * CAP + r] = (int)(((uint)(524287 - r) << 13) | (uint)fj2);
                keys[fj2] = INFINITY;
            }
            __syncthreads();
        }
        if (t == 0) cnt_g[row] = 64;
        __syncthreads();
    }
}

// ---------------- K3: refine v3 (64-bit-safe bisection midpoints) ----------------
__global__ __launch_bounds__(256) void refine_kernel(
    const float* __restrict__ feats, const double* __restrict__ sqd,
    const int* __restrict__ cand, const int* __restrict__ cnt_g,
    int* __restrict__ fidx, float* __restrict__ fscr) {
    __shared__ float fi_s[4][DIM];
    __shared__ int   sel_s[4][RSEL];
    const int w = threadIdx.x >> 6, l = threadIdx.x & 63;
    const int i = blockIdx.x * 4 + w;
    *reinterpret_cast<float4*>(&fi_s[w][l * 4]) =
        *reinterpret_cast<const float4*>(feats + (size_t)i * DIM + l * 4);
    __syncthreads();                     // only barrier; waves diverge after
    const int nc   = min(cnt_g[i], CAP);
    const int want = min(nc, RSEL);
    const int* crow = cand + (size_t)i * CAP;
    uint pk[4]; bool act[4];
#pragma unroll
    for (int b = 0; b < 4; ++b) {
        const int c = b * 64 + l;
        act[b] = (c < nc);
        pk[b]  = act[b] ? (uint)crow[c] : 0u;
    }
    // (1) bisect: largest T with count(act && pk >= T) >= want (64-bit midpoint)
    uint lo = 0u, hi = 0xffffffffu;
    while (lo < hi) {
        const uint mid = (uint)(((ull)lo + (ull)hi + 1ULL) >> 1);
        int c = 0;
#pragma unroll
        for (int b = 0; b < 4; ++b) c += __popcll(__ballot(act[b] && pk[b] >= mid));
        if (c >= want) lo = mid; else hi = mid - 1u;
    }
    // (2) compact selected j-indices to sel_s[w][0..want)
    {
        int base = 0;
#pragma unroll
        for (int b = 0; b < 4; ++b) {
            const bool s = act[b] && pk[b] >= lo;
            const ull bal = __ballot(s);
            const int pos = base + __popcll(bal & ((1ULL << l) - 1ULL));
            if (s && pos < RSEL) sel_s[w][pos] = (int)(pk[b] & 8191u);
            base += __popcll(bal);
        }
    }
    // (3) fp64 dot for lanes < want
    const bool mine = (l < want);
    const int  j    = mine ? sel_s[w][l] : i;
    double dot0 = 0.0, dot1 = 0.0, dot2 = 0.0, dot3 = 0.0;
    if (mine) {
        const float* fj = feats + (size_t)j * DIM;
#pragma unroll 8
        for (int dq = 0; dq < DIM / 8; ++dq) {
            const float4 a0 = *reinterpret_cast<const float4*>(&fi_s[w][dq * 8]);
            const float4 a1 = *reinterpret_cast<const float4*>(&fi_s[w][dq * 8 + 4]);
            const float4 b0 = *reinterpret_cast<const float4*>(fj + dq * 8);
            const float4 b1 = *reinterpret_cast<const float4*>(fj + dq * 8 + 4);
            dot0 += (double)a0.x * b0.x + (double)a0.y * b0.y;
            dot1 += (double)a0.z * b0.z + (double)a0.w * b0.w;
            dot2 += (double)a1.x * b1.x + (double)a1.y * b1.y;
            dot3 += (double)a1.z * b1.z + (double)a1.w * b1.w;
        }
    }
    const double dot = (dot0 + dot1) + (dot2 + dot3);
    const double dd  = sqd[i] + sqd[j] - 2.0 * dot;   // the np-reference formula
    // (4) 17-smallest by composite key (dd bits | idx)
    const ull key = mine ? ((ull)(__double_as_longlong(fmax(dd, 0.0)) & ~8191LL)
                            | (ull)(uint)j)
                         : ~0ULL;
    ull klo = 0ULL, khi = 0x4330000000000000ULL;
    while (klo < khi) {
        const ull mid = klo + ((khi - klo) >> 1);
        const int c = __popcll(__ballot(key <= mid));
        if (c >= NSLOT) khi = mid; else klo = mid + 1ULL;
    }
    const bool s2 = (key <= khi);
    const ull bal = __ballot(s2);
    const int pos = __popcll(bal & ((1ULL << l) - 1ULL));
    if (s2 && pos < NSLOT) {
        fidx[(size_t)i * NSLOT + pos] = j;
        fscr[(size_t)i * NSLOT + pos] = (float)dot;
    }
}

// ---------------- K4: mutual mask + sparse softmax + mix + normalize ----------------
__global__ void fcm_out_kernel(const float* __restrict__ feats,
                               const int* __restrict__ knn_idx,
                               const float* __restrict__ knn_scr,
                               float* __restrict__ out) {
    const int w    = threadIdx.x >> 6;
    const int lane = threadIdx.x & 63;
    const int i    = blockIdx.x * 4 + w;

    int jt = -1; float st = 0.f; bool valid = false;
    if (lane < NSLOT) {
        jt = knn_idx[(size_t)i * NSLOT + lane];
        st = knn_scr[(size_t)i * NSLOT + lane];
        if (jt != i) {
            const int* nb = knn_idx + (size_t)jt * NSLOT;
#pragma unroll
            for (int s = 0; s < NSLOT; ++s) valid |= (nb[s] == i);
        }
    }
    float val = valid ? st : -INFINITY;
#pragma unroll
    for (int off = 32; off > 0; off >>= 1) val = fmaxf(val, __shfl_xor(val, off, 64));
    const float m  = fmaxf(1.0f, val);
    const float wt = valid ? expf(st - m) : 0.f;
    float ws = wt;
#pragma unroll
    for (int off = 32; off > 0; off >>= 1) ws += __shfl_xor(ws, off, 64);
    const float wdiag = expf(1.0f - m);
    const float inv   = 1.0f / (ws + wdiag);

    const float4 fi = *reinterpret_cast<const float4*>(feats + (size_t)i * DIM + lane * 4);
    float ax = fi.x * wdiag, ay = fi.y * wdiag, az = fi.z * wdiag, aw = fi.w * wdiag;
    for (int t = 0; t < NSLOT; ++t) {
        const float wtt = __shfl(wt, t, 64);
        const int   jj  = __shfl(jt, t, 64);
        if (wtt > 0.f) {
            const float4 fj = *reinterpret_cast<const float4*>(feats + (size_t)jj * DIM + lane * 4);
            ax = fmaf(wtt, fj.x, ax); ay = fmaf(wtt, fj.y, ay);
            az = fmaf(wtt, fj.z, az); aw = fmaf(wtt, fj.w, aw);
        }
    }
    const float ox = fmaf(ax, inv, fi.x), oy = fmaf(ay, inv, fi.y);
    const float oz = fmaf(az, inv, fi.z), ow = fmaf(aw, inv, fi.w);
    float nn = ox * ox + oy * oy + oz * oz + ow * ow;
#pragma unroll
    for (int off = 32; off > 0; off >>= 1) nn += __shfl_xor(nn, off, 64);
    const float scl = 1.0f / fmaxf(sqrtf(nn), 1e-12f);
    float4 o; o.x = ox * scl; o.y = oy * scl; o.z = oz * scl; o.w = ow * scl;
    *reinterpret_cast<float4*>(out + (size_t)i * DIM + lane * 4) = o;
}

extern "C" void kernel_launch(void* const* d_in, const int* in_sizes, int n_in,
                              void* d_out, int out_size, void* d_ws, size_t ws_size,
                              hipStream_t stream) {
    (void)in_sizes; (void)n_in; (void)out_size; (void)ws_size;
    const float* feats = (const float*)d_in[0];
    float* out = (float*)d_out;
    char* ws = (char*)d_ws;
    size_t off = 0;
    float*  sq    = (float*) (ws + off); off += NPTS * 4;                 // 32 KB
    double* sqd   = (double*)(ws + off); off += NPTS * 8;                 // 64 KB
    float*  musig = (float*) (ws + off); off += 128;
    ushort* fbp   = (ushort*)(ws + off); off += (size_t)NPTS * DIM * 2;   // 4 MB packed
    int*    cand  = (int*)   (ws + off); off += (size_t)NPTS * CAP * 4;   // 8 MB
    int*    cnt_g = (int*)   (ws + off); off += NPTS * 4;
    int*    fidx  = (int*)   (ws + off); off += NPTS * NSLOT * 4;
    float*  fscr  = (float*) (ws + off); off += NPTS * NSLOT * 4;

    pack_kernel<<<NPTS / 64, 256, 0, stream>>>(feats, fbp, sq, sqd, cnt_g);
    stats_kernel<<<1, 1024, 0, stream>>>(sq, musig);
    gemm_select_kernel<<<(NPTS / 32) * 4, 512, 0, stream>>>(fbp, sq, musig, cand, cnt_g);
    fallback_kernel<<<NPTS / 256, 256, 0, stream>>>(feats, sq, cand, cnt_g);
    refine_kernel<<<NPTS / 4, 256, 0, stream>>>(feats, sqd, cand, cnt_g, fidx, fscr);
    fcm_out_kernel<<<NPTS / 4, 256, 0, stream>>>(feats, fidx, fscr, out);
}

// Round 22
// 119.732 us; speedup vs baseline: 1.1407x; 1.1407x over previous
//
#include <hip/hip_runtime.h>
#include <math.h>

// FCM mutual-kNN attention mixing. N=8192, D=256, K=16.  [round-19 verbatim]
//   K1 pack:   feats -> fbp fragment order + fp64 row sqnorms + zero cnt_g
//   K1b stats: deterministic reduction of sq -> mu/var
//   K2 gemm:   A panel contiguous in LDS, B coalesced fragment stream with
//              DEPTH-2 slot-reuse prefetch, barrier-free; threshold select.
//   K2b fallback: parallel scan for bad rows + full-rescan repair (expected 0)
//   K3 refine: top-24 by packed key -> fp64 dot (np formula) -> exact top-17
//   K4 out:    mutual mask + sparse softmax + mix + normalize
#define NPTS 8192
#define DIM  256
#define NSLOT 17
#define CAP  256
#define LCAP 48
#define RSEL 24
#define ZTH  (-2.45f)
typedef unsigned int uint;
typedef unsigned short ushort;
typedef unsigned long long ull;
typedef __attribute__((ext_vector_type(8))) short bf16x8;
typedef __attribute__((ext_vector_type(4))) float f32x4;

__device__ __forceinline__ ushort f2bf(float f) {
    uint x = __float_as_uint(f);
    return (ushort)((x + 0x7fffu + ((x >> 16) & 1u)) >> 16);
}

// ---------------- K1: pack feats -> fragment order + fp64 sqnorms + cnt_g=0 ----------------
__global__ void pack_kernel(const float* __restrict__ feats, ushort* __restrict__ fbp,
                            float* __restrict__ sq, double* __restrict__ sqd,
                            int* __restrict__ cnt_g) {
    const int cb = (blockIdx.x * 256 + threadIdx.x) >> 6;   // global wave id
    const int l  = threadIdx.x & 63;
    const int l15 = l & 15, lg = l >> 4;
    const float* src = feats + (size_t)(cb * 16 + l15) * DIM + lg * 8;
    ushort* dst = fbp + (size_t)cb * 4096 + l * 8;
    double pd = 0.0;
#pragma unroll
    for (int kb = 0; kb < 8; ++kb) {
        const float4 v0 = *reinterpret_cast<const float4*>(src + kb * 32);
        const float4 v1 = *reinterpret_cast<const float4*>(src + kb * 32 + 4);
        pd += (double)v0.x * v0.x + (double)v0.y * v0.y +
              (double)v0.z * v0.z + (double)v0.w * v0.w;
        pd += (double)v1.x * v1.x + (double)v1.y * v1.y +
              (double)v1.z * v1.z + (double)v1.w * v1.w;
        bf16x8 bv;
        bv[0] = (short)f2bf(v0.x); bv[1] = (short)f2bf(v0.y);
        bv[2] = (short)f2bf(v0.z); bv[3] = (short)f2bf(v0.w);
        bv[4] = (short)f2bf(v1.x); bv[5] = (short)f2bf(v1.y);
        bv[6] = (short)f2bf(v1.z); bv[7] = (short)f2bf(v1.w);
        *reinterpret_cast<bf16x8*>(dst + kb * 512) = bv;
    }
    pd += __shfl_xor(pd, 16, 64);
    pd += __shfl_xor(pd, 32, 64);
    if (lg == 0) {
        const int row = cb * 16 + l15;
        sq[row] = (float)pd; sqd[row] = pd; cnt_g[row] = 0;
    }
}

// ---------------- K1b: deterministic stats (mu, var) ----------------
__global__ void stats_kernel(const float* __restrict__ sq, float* __restrict__ musig) {
    __shared__ double s0s[16], s1s[16];
    const int t = threadIdx.x, lane = t & 63, w = t >> 6;
    double s0 = 0.0, s1 = 0.0;
    for (int r = t; r < NPTS; r += 1024) {
        const double v = (double)sq[r];
        s0 += v; s1 += v * v;
    }
#pragma unroll
    for (int off = 32; off > 0; off >>= 1) {
        s0 += __shfl_down(s0, off, 64);
        s1 += __shfl_down(s1, off, 64);
    }
    if (lane == 0) { s0s[w] = s0; s1s[w] = s1; }
    __syncthreads();
    if (t == 0) {
        double a0 = 0.0, a1 = 0.0;
#pragma unroll
        for (int q = 0; q < 16; ++q) { a0 += s0s[q]; a1 += s1s[q]; }
        const double mu = a0 / NPTS;
        const double var = a1 / NPTS - mu * mu;
        musig[0] = (float)mu;
        musig[1] = (float)fmax(var, 1.0);
    }
}

// ---------------- K2: barrier-free MFMA GEMM + fused threshold select ----------------
// 512 thr = 8 waves. Block: 64 rows x 2048-col quarter. Depth-2 B prefetch:
// per step, MFMA(bb[ks&1]) first, then load frag(c+2) into the SAME slot.
__global__ __launch_bounds__(512, 2) void gemm_select_kernel(
    const ushort* __restrict__ fbp, const float* __restrict__ sq,
    const float* __restrict__ musig, int* __restrict__ cand, int* __restrict__ cnt_g) {
    __shared__ ushort As[16384];         // 32 KB fragment-ordered A panel
    __shared__ int    cbuf[64][LCAP];    // 12 KB packed (keyq<<13)|idx
    __shared__ float  Ts[64], sqi_s[64];
    __shared__ int    cnt[64];
    __shared__ int    base_s[64], n_s[64];

    const int tid = threadIdx.x;
    const int w   = tid >> 6;
    const int l   = tid & 63;
    const int l15 = l & 15, lg = l >> 4;
    const int rowblk = (blockIdx.x >> 3) * 2 + (blockIdx.x & 1);
    const int row0   = rowblk * 64;
    const int Jbase  = ((blockIdx.x & 7) >> 1) * 2048;

    if (tid < 64) {
        const float mu  = musig[0];
        const float var = musig[1];
        const float qi  = sq[row0 + tid];
        sqi_s[tid] = qi;
        Ts[tid]    = qi + mu + ZTH * sqrtf(var + 4.f * qi);
        cnt[tid]   = 0;
    }
    {   // stage A panel: straight 32KB copy (4 colblks of fbp)
        const ushort* src = fbp + (size_t)(row0 >> 4) * 4096;
#pragma unroll
        for (int s = 0; s < 4; ++s) {
            const int idx = tid + s * 512;
            *reinterpret_cast<bf16x8*>(As + idx * 8) =
                *reinterpret_cast<const bf16x8*>(src + (size_t)idx * 8);
        }
    }
    __syncthreads();                     // the ONLY barrier before the merge

    const int gcol = w * 32;
    const ushort* bp = fbp + (size_t)((Jbase >> 4) + w * 2) * 4096 + l * 8;

    bf16x8 bb[2][2];
#pragma unroll
    for (int cf = 0; cf < 2; ++cf) {
        bb[0][cf] = *reinterpret_cast<const bf16x8*>(bp + cf * 4096);          // chunk 0
        bb[1][cf] = *reinterpret_cast<const bf16x8*>(bp + cf * 4096 + 512);    // chunk 1
    }

    for (int tile = 0; tile < 8; ++tile) {
        f32x4 acc[4][2];
#pragma unroll
        for (int mf = 0; mf < 4; ++mf) {
            acc[mf][0] = (f32x4){0.f, 0.f, 0.f, 0.f};
            acc[mf][1] = (f32x4){0.f, 0.f, 0.f, 0.f};
        }
#pragma unroll
        for (int ks = 0; ks < 8; ++ks) {
            const int cur = ks & 1;
            bf16x8 af[4];
#pragma unroll
            for (int mf = 0; mf < 4; ++mf)
                af[mf] = *reinterpret_cast<const bf16x8*>(
                    As + ((mf * 8 + ks) * 64 + l) * 8);
#pragma unroll
            for (int mf = 0; mf < 4; ++mf) {
                acc[mf][0] = __builtin_amdgcn_mfma_f32_16x16x32_bf16(af[mf], bb[cur][0], acc[mf][0], 0, 0, 0);
                acc[mf][1] = __builtin_amdgcn_mfma_f32_16x16x32_bf16(af[mf], bb[cur][1], acc[mf][1], 0, 0, 0);
            }
            // depth-2 prefetch: frag(c+2) into the slot just consumed
            if (tile < 7 || ks < 6) {
                const int ntile = (ks >= 6) ? tile + 1 : tile;
                const int nks   = (ks + 2) & 7;
#pragma unroll
                for (int cf = 0; cf < 2; ++cf)
                    bb[cur][cf] = *reinterpret_cast<const bf16x8*>(
                        bp + (size_t)ntile * 65536 + cf * 4096 + nks * 512);
            }
        }
        // ---- per-tile epilogue: threshold select, packed into LDS cbuf ----
        const int Jt = Jbase + tile * 256;
        float sqc[2];
#pragma unroll
        for (int cf = 0; cf < 2; ++cf) sqc[cf] = sq[Jt + gcol + cf * 16 + l15];
#pragma unroll
        for (int mf = 0; mf < 4; ++mf)
#pragma unroll
            for (int cf = 0; cf < 2; ++cf)
#pragma unroll
                for (int r = 0; r < 4; ++r) {
                    const int row = mf * 16 + lg * 4 + r;
                    const float tt = Ts[row];
                    const float key = sqi_s[row] + sqc[cf] - 2.f * acc[mf][cf][r];
                    if (key < tt) {
                        const int kq2 = min((int)((tt - key) * 4096.f), 524287);
                        const uint val = ((uint)max(kq2, 0) << 13) |
                                         (uint)(Jt + gcol + cf * 16 + l15);
                        const int pos = atomicAdd(&cnt[row], 1);
                        if (pos < LCAP) cbuf[row][pos] = (int)val;
                    }
                }
    }
    __syncthreads();
    if (tid < 64) {
        const int local = cnt[tid];
        const int n = min(local, LCAP);
        const int add = (local > LCAP) ? (n + (1 << 20)) : n;   // poison on overflow
        base_s[tid] = atomicAdd(&cnt_g[row0 + tid], add);
        n_s[tid] = n;
    }
    __syncthreads();
    for (int s = tid; s < 64 * LCAP; s += 512) {
        const int r = s / LCAP, k2 = s - r * LCAP;
        if (k2 < n_s[r]) {
            const int b = base_s[r] + k2;
            if (b < CAP) cand[(size_t)(row0 + r) * CAP + b] = cbuf[r][k2];
        }
    }
}

// ---------------- K2b: parallel bad-row scan + repair (expected none) ----------------
__global__ void fallback_kernel(const float* __restrict__ feats, const float* __restrict__ sq,
                                int* __restrict__ cand, int* __restrict__ cnt_g) {
    __shared__ float fi_s[DIM];
    __shared__ float keys[NPTS];
    __shared__ float rkey[4];
    __shared__ int   rid[4];
    __shared__ int   badlist[256];
    __shared__ int   nbad_s;
    const int t = threadIdx.x;
    if (t == 0) nbad_s = 0;
    __syncthreads();
    {
        const int myrow = blockIdx.x * 256 + t;
        const int v = cnt_g[myrow];
        if (v < NSLOT || v > CAP) badlist[atomicAdd(&nbad_s, 1)] = myrow;
    }
    __syncthreads();
    const int nb = nbad_s;
    for (int bi = 0; bi < nb; ++bi) {
        const int row = badlist[bi];
        fi_s[t] = feats[(size_t)row * DIM + t];
        __syncthreads();
        const float sqi = sq[row];
        for (int p = 0; p < NPTS / 256; ++p) {
            const int jj = p * 256 + t;
            const float* fj = feats + (size_t)jj * DIM;
            float d = 0.f;
            for (int dq = 0; dq < DIM / 4; ++dq) {
                const float4 b4 = *reinterpret_cast<const float4*>(fj + dq * 4);
                const float4 a4 = *reinterpret_cast<const float4*>(&fi_s[dq * 4]);
                d = fmaf(a4.x, b4.x, fmaf(a4.y, b4.y, fmaf(a4.z, b4.z, fmaf(a4.w, b4.w, d))));
            }
            keys[jj] = sqi + sq[jj] - 2.f * d;
        }
        __syncthreads();
        for (int r = 0; r < 64; ++r) {
            float bk = INFINITY; int bj = 0x7fffffff;
            for (int p = 0; p < NPTS / 256; ++p) {
                const int jj = p * 256 + t;
                const float kv = keys[jj];
                if (kv < bk || (kv == bk && jj < bj)) { bk = kv; bj = jj; }
            }
#pragma unroll
            for (int off = 1; off <= 32; off <<= 1) {
                const float ok = __shfl_xor(bk, off, 64);
                const int   oj = __shfl_xor(bj, off, 64);
                if (ok < bk || (ok == bk && oj < bj)) { bk = ok; bj = oj; }
            }
            if ((t & 63) == 0) { rkey[t >> 6] = bk; rid[t >> 6] = bj; }
            __syncthreads();
            float fk = rkey[0]; int fj2 = rid[0];
#pragma unroll
            for (int q = 1; q < 4; ++q)
                if (rkey[q] < fk || (rkey[q] == fk && rid[q] < fj2)) { fk = rkey[q]; fj2 = rid[q]; }
            if (t == 0) {   // rank-ordered packed key (idx in low 13 bits)
                cand[(size_t)row * CAP + r] = (int)(((uint)(524287 - r) << 13) | (uint)fj2);
                keys[fj2] = INFINITY;
            }
            __syncthreads();
        }
        if (t == 0) cnt_g[row] = 64;
        __syncthreads();
    }
}

// ---------------- K3: refine v3 (64-bit-safe bisection midpoints) ----------------
__global__ __launch_bounds__(256) void refine_kernel(
    const float* __restrict__ feats, const double* __restrict__ sqd,
    const int* __restrict__ cand, const int* __restrict__ cnt_g,
    int* __restrict__ fidx, float* __restrict__ fscr) {
    __shared__ float fi_s[4][DIM];
    __shared__ int   sel_s[4][RSEL];
    const int w = threadIdx.x >> 6, l = threadIdx.x & 63;
    const int i = blockIdx.x * 4 + w;
    *reinterpret_cast<float4*>(&fi_s[w][l * 4]) =
        *reinterpret_cast<const float4*>(feats + (size_t)i * DIM + l * 4);
    __syncthreads();                     // only barrier; waves diverge after
    const int nc   = min(cnt_g[i], CAP);
    const int want = min(nc, RSEL);
    const int* crow = cand + (size_t)i * CAP;
    uint pk[4]; bool act[4];
#pragma unroll
    for (int b = 0; b < 4; ++b) {
        const int c = b * 64 + l;
        act[b] = (c < nc);
        pk[b]  = act[b] ? (uint)crow[c] : 0u;
    }
    // (1) bisect: largest T with count(act && pk >= T) >= want (64-bit midpoint)
    uint lo = 0u, hi = 0xffffffffu;
    while (lo < hi) {
        const uint mid = (uint)(((ull)lo + (ull)hi + 1ULL) >> 1);
        int c = 0;
#pragma unroll
        for (int b = 0; b < 4; ++b) c += __popcll(__ballot(act[b] && pk[b] >= mid));
        if (c >= want) lo = mid; else hi = mid - 1u;
    }
    // (2) compact selected j-indices to sel_s[w][0..want)
    {
        int base = 0;
#pragma unroll
        for (int b = 0; b < 4; ++b) {
            const bool s = act[b] && pk[b] >= lo;
            const ull bal = __ballot(s);
            const int pos = base + __popcll(bal & ((1ULL << l) - 1ULL));
            if (s && pos < RSEL) sel_s[w][pos] = (int)(pk[b] & 8191u);
            base += __popcll(bal);
        }
    }
    // (3) fp64 dot for lanes < want
    const bool mine = (l < want);
    const int  j    = mine ? sel_s[w][l] : i;
    double dot0 = 0.0, dot1 = 0.0, dot2 = 0.0, dot3 = 0.0;
    if (mine) {
        const float* fj = feats + (size_t)j * DIM;
#pragma unroll 8
        for (int dq = 0; dq < DIM / 8; ++dq) {
            const float4 a0 = *reinterpret_cast<const float4*>(&fi_s[w][dq * 8]);
            const float4 a1 = *reinterpret_cast<const float4*>(&fi_s[w][dq * 8 + 4]);
            const float4 b0 = *reinterpret_cast<const float4*>(fj + dq * 8);
            const float4 b1 = *reinterpret_cast<const float4*>(fj + dq * 8 + 4);
            dot0 += (double)a0.x * b0.x + (double)a0.y * b0.y;
            dot1 += (double)a0.z * b0.z + (double)a0.w * b0.w;
            dot2 += (double)a1.x * b1.x + (double)a1.y * b1.y;
            dot3 += (double)a1.z * b1.z + (double)a1.w * b1.w;
        }
    }
    const double dot = (dot0 + dot1) + (dot2 + dot3);
    const double dd  = sqd[i] + sqd[j] - 2.0 * dot;   // the np-reference formula
    // (4) 17-smallest by composite key (dd bits | idx)
    const ull key = mine ? ((ull)(__double_as_longlong(fmax(dd, 0.0)) & ~8191LL)
                            | (ull)(uint)j)
                         : ~0ULL;
    ull klo = 0ULL, khi = 0x4330000000000000ULL;
    while (klo < khi) {
        const ull mid = klo + ((khi - klo) >> 1);
        const int c = __popcll(__ballot(key <= mid));
        if (c >= NSLOT) khi = mid; else klo = mid + 1ULL;
    }
    const bool s2 = (key <= khi);
    const ull bal = __ballot(s2);
    const int pos = __popcll(bal & ((1ULL << l) - 1ULL));
    if (s2 && pos < NSLOT) {
        fidx[(size_t)i * NSLOT + pos] = j;
        fscr[(size_t)i * NSLOT + pos] = (float)dot;
    }
}

// ---------------- K4: mutual mask + sparse softmax + mix + normalize ----------------
__global__ void fcm_out_kernel(const float* __restrict__ feats,
                               const int* __restrict__ knn_idx,
                               const float* __restrict__ knn_scr,
                               float* __restrict__ out) {
    const int w    = threadIdx.x >> 6;
    const int lane = threadIdx.x & 63;
    const int i    = blockIdx.x * 4 + w;

    int jt = -1; float st = 0.f; bool valid = false;
    if (lane < NSLOT) {
        jt = knn_idx[(size_t)i * NSLOT + lane];
        st = knn_scr[(size_t)i * NSLOT + lane];
        if (jt != i) {
            const int* nb = knn_idx + (size_t)jt * NSLOT;
#pragma unroll
            for (int s = 0; s < NSLOT; ++s) valid |= (nb[s] == i);
        }
    }
    float val = valid ? st : -INFINITY;
#pragma unroll
    for (int off = 32; off > 0; off >>= 1) val = fmaxf(val, __shfl_xor(val, off, 64));
    const float m  = fmaxf(1.0f, val);
    const float wt = valid ? expf(st - m) : 0.f;
    float ws = wt;
#pragma unroll
    for (int off = 32; off > 0; off >>= 1) ws += __shfl_xor(ws, off, 64);
    const float wdiag = expf(1.0f - m);
    const float inv   = 1.0f / (ws + wdiag);

    const float4 fi = *reinterpret_cast<const float4*>(feats + (size_t)i * DIM + lane * 4);
    float ax = fi.x * wdiag, ay = fi.y * wdiag, az = fi.z * wdiag, aw = fi.w * wdiag;
    for (int t = 0; t < NSLOT; ++t) {
        const float wtt = __shfl(wt, t, 64);
        const int   jj  = __shfl(jt, t, 64);
        if (wtt > 0.f) {
            const float4 fj = *reinterpret_cast<const float4*>(feats + (size_t)jj * DIM + lane * 4);
            ax = fmaf(wtt, fj.x, ax); ay = fmaf(wtt, fj.y, ay);
            az = fmaf(wtt, fj.z, az); aw = fmaf(wtt, fj.w, aw);
        }
    }
    const float ox = fmaf(ax, inv, fi.x), oy = fmaf(ay, inv, fi.y);
    const float oz = fmaf(az, inv, fi.z), ow = fmaf(aw, inv, fi.w);
    float nn = ox * ox + oy * oy + oz * oz + ow * ow;
#pragma unroll
    for (int off = 32; off > 0; off >>= 1) nn += __shfl_xor(nn, off, 64);
    const float scl = 1.0f / fmaxf(sqrtf(nn), 1e-12f);
    float4 o; o.x = ox * scl; o.y = oy * scl; o.z = oz * scl; o.w = ow * scl;
    *reinterpret_cast<float4*>(out + (size_t)i * DIM + lane * 4) = o;
}

extern "C" void kernel_launch(void* const* d_in, const int* in_sizes, int n_in,
                              void* d_out, int out_size, void* d_ws, size_t ws_size,
                              hipStream_t stream) {
    (void)in_sizes; (void)n_in; (void)out_size; (void)ws_size;
    const float* feats = (const float*)d_in[0];
    float* out = (float*)d_out;
    char* ws = (char*)d_ws;
    size_t off = 0;
    float*  sq    = (float*) (ws + off); off += NPTS * 4;                 // 32 KB
    double* sqd   = (double*)(ws + off); off += NPTS * 8;                 // 64 KB
    float*  musig = (float*) (ws + off); off += 128;
    ushort* fbp   = (ushort*)(ws + off); off += (size_t)NPTS * DIM * 2;   // 4 MB packed
    int*    cand  = (int*)   (ws + off); off += (size_t)NPTS * CAP * 4;   // 8 MB
    int*    cnt_g = (int*)   (ws + off); off += NPTS * 4;
    int*    fidx  = (int*)   (ws + off); off += NPTS * NSLOT * 4;
    float*  fscr  = (float*) (ws + off); off += NPTS * NSLOT * 4;

    pack_kernel<<<NPTS / 64, 256, 0, stream>>>(feats, fbp, sq, sqd, cnt_g);
    stats_kernel<<<1, 1024, 0, stream>>>(sq, musig);
    gemm_select_kernel<<<(NPTS / 64) * 4, 512, 0, stream>>>(fbp, sq, musig, cand, cnt_g);
    fallback_kernel<<<NPTS / 256, 256, 0, stream>>>(feats, sq, cand, cnt_g);
    refine_kernel<<<NPTS / 4, 256, 0, stream>>>(feats, sqd, cand, cnt_g, fidx, fscr);
    fcm_out_kernel<<<NPTS / 4, 256, 0, stream>>>(feats, fidx, fscr, out);
}

// Round 23
// 112.502 us; speedup vs baseline: 1.2140x; 1.0643x over previous
//
#include <hip/hip_runtime.h>
#include <math.h>

// FCM mutual-kNN attention mixing. N=8192, D=256, K=16.
//   K1 pack:   feats -> fbp fragment order + fp64 row sqnorms (256 blks x 128)
//   K1b stats: deterministic reduction of sq -> mu/var
//   K2 gemm:   [r19 verbatim] A panel in LDS, B fragment stream depth-2,
//              barrier-free; threshold select -> packed LDS cbuf -> merge.
//   K2b fallback: parallel scan for bad rows + full-rescan repair (expected 0)
//   K3 refine: top-24 by packed key -> fp64 dot with 2 lanes/cand -> top-17
//   K4 out:    mutual mask + sparse softmax + mix + normalize
#define NPTS 8192
#define DIM  256
#define NSLOT 17
#define CAP  256
#define LCAP 48
#define RSEL 24
#define ZTH  (-2.45f)
typedef unsigned int uint;
typedef unsigned short ushort;
typedef unsigned long long ull;
typedef __attribute__((ext_vector_type(8))) short bf16x8;
typedef __attribute__((ext_vector_type(4))) float f32x4;

__device__ __forceinline__ ushort f2bf(float f) {
    uint x = __float_as_uint(f);
    return (ushort)((x + 0x7fffu + ((x >> 16) & 1u)) >> 16);
}

// ---------------- K1: pack feats -> fragment order + fp64 sqnorms + cnt_g=0 ----------------
// 256 blocks x 128 thr (2 waves): every CU gets work.
__global__ void pack_kernel(const float* __restrict__ feats, ushort* __restrict__ fbp,
                            float* __restrict__ sq, double* __restrict__ sqd,
                            int* __restrict__ cnt_g) {
    const int cb = (blockIdx.x * 128 + threadIdx.x) >> 6;   // global wave id
    const int l  = threadIdx.x & 63;
    const int l15 = l & 15, lg = l >> 4;
    const float* src = feats + (size_t)(cb * 16 + l15) * DIM + lg * 8;
    ushort* dst = fbp + (size_t)cb * 4096 + l * 8;
    double pd = 0.0;
#pragma unroll
    for (int kb = 0; kb < 8; ++kb) {
        const float4 v0 = *reinterpret_cast<const float4*>(src + kb * 32);
        const float4 v1 = *reinterpret_cast<const float4*>(src + kb * 32 + 4);
        pd += (double)v0.x * v0.x + (double)v0.y * v0.y +
              (double)v0.z * v0.z + (double)v0.w * v0.w;
        pd += (double)v1.x * v1.x + (double)v1.y * v1.y +
              (double)v1.z * v1.z + (double)v1.w * v1.w;
        bf16x8 bv;
        bv[0] = (short)f2bf(v0.x); bv[1] = (short)f2bf(v0.y);
        bv[2] = (short)f2bf(v0.z); bv[3] = (short)f2bf(v0.w);
        bv[4] = (short)f2bf(v1.x); bv[5] = (short)f2bf(v1.y);
        bv[6] = (short)f2bf(v1.z); bv[7] = (short)f2bf(v1.w);
        *reinterpret_cast<bf16x8*>(dst + kb * 512) = bv;
    }
    pd += __shfl_xor(pd, 16, 64);
    pd += __shfl_xor(pd, 32, 64);
    if (lg == 0) {
        const int row = cb * 16 + l15;
        sq[row] = (float)pd; sqd[row] = pd; cnt_g[row] = 0;
    }
}

// ---------------- K1b: deterministic stats (mu, var) ----------------
__global__ void stats_kernel(const float* __restrict__ sq, float* __restrict__ musig) {
    __shared__ double s0s[16], s1s[16];
    const int t = threadIdx.x, lane = t & 63, w = t >> 6;
    double s0 = 0.0, s1 = 0.0;
    for (int r = t; r < NPTS; r += 1024) {
        const double v = (double)sq[r];
        s0 += v; s1 += v * v;
    }
#pragma unroll
    for (int off = 32; off > 0; off >>= 1) {
        s0 += __shfl_down(s0, off, 64);
        s1 += __shfl_down(s1, off, 64);
    }
    if (lane == 0) { s0s[w] = s0; s1s[w] = s1; }
    __syncthreads();
    if (t == 0) {
        double a0 = 0.0, a1 = 0.0;
#pragma unroll
        for (int q = 0; q < 16; ++q) { a0 += s0s[q]; a1 += s1s[q]; }
        const double mu = a0 / NPTS;
        const double var = a1 / NPTS - mu * mu;
        musig[0] = (float)mu;
        musig[1] = (float)fmax(var, 1.0);
    }
}

// ---------------- K2: barrier-free MFMA GEMM + fused threshold select ----------------
// [r19 verbatim] 512 thr = 8 waves. Block: 64 rows x 2048-col quarter.
__global__ __launch_bounds__(512, 2) void gemm_select_kernel(
    const ushort* __restrict__ fbp, const float* __restrict__ sq,
    const float* __restrict__ musig, int* __restrict__ cand, int* __restrict__ cnt_g) {
    __shared__ ushort As[16384];         // 32 KB fragment-ordered A panel
    __shared__ int    cbuf[64][LCAP];    // 12 KB packed (keyq<<13)|idx
    __shared__ float  Ts[64], sqi_s[64];
    __shared__ int    cnt[64];
    __shared__ int    base_s[64], n_s[64];

    const int tid = threadIdx.x;
    const int w   = tid >> 6;
    const int l   = tid & 63;
    const int l15 = l & 15, lg = l >> 4;
    const int rowblk = (blockIdx.x >> 3) * 2 + (blockIdx.x & 1);
    const int row0   = rowblk * 64;
    const int Jbase  = ((blockIdx.x & 7) >> 1) * 2048;

    if (tid < 64) {
        const float mu  = musig[0];
        const float var = musig[1];
        const float qi  = sq[row0 + tid];
        sqi_s[tid] = qi;
        Ts[tid]    = qi + mu + ZTH * sqrtf(var + 4.f * qi);
        cnt[tid]   = 0;
    }
    {   // stage A panel: straight 32KB copy (4 colblks of fbp)
        const ushort* src = fbp + (size_t)(row0 >> 4) * 4096;
#pragma unroll
        for (int s = 0; s < 4; ++s) {
            const int idx = tid + s * 512;
            *reinterpret_cast<bf16x8*>(As + idx * 8) =
                *reinterpret_cast<const bf16x8*>(src + (size_t)idx * 8);
        }
    }
    __syncthreads();                     // the ONLY barrier before the merge

    const int gcol = w * 32;
    const ushort* bp = fbp + (size_t)((Jbase >> 4) + w * 2) * 4096 + l * 8;

    bf16x8 bb[2][2];
#pragma unroll
    for (int cf = 0; cf < 2; ++cf) {
        bb[0][cf] = *reinterpret_cast<const bf16x8*>(bp + cf * 4096);          // chunk 0
        bb[1][cf] = *reinterpret_cast<const bf16x8*>(bp + cf * 4096 + 512);    // chunk 1
    }

    for (int tile = 0; tile < 8; ++tile) {
        f32x4 acc[4][2];
#pragma unroll
        for (int mf = 0; mf < 4; ++mf) {
            acc[mf][0] = (f32x4){0.f, 0.f, 0.f, 0.f};
            acc[mf][1] = (f32x4){0.f, 0.f, 0.f, 0.f};
        }
#pragma unroll
        for (int ks = 0; ks < 8; ++ks) {
            const int cur = ks & 1;
            bf16x8 af[4];
#pragma unroll
            for (int mf = 0; mf < 4; ++mf)
                af[mf] = *reinterpret_cast<const bf16x8*>(
                    As + ((mf * 8 + ks) * 64 + l) * 8);
#pragma unroll
            for (int mf = 0; mf < 4; ++mf) {
                acc[mf][0] = __builtin_amdgcn_mfma_f32_16x16x32_bf16(af[mf], bb[cur][0], acc[mf][0], 0, 0, 0);
                acc[mf][1] = __builtin_amdgcn_mfma_f32_16x16x32_bf16(af[mf], bb[cur][1], acc[mf][1], 0, 0, 0);
            }
            // depth-2 prefetch: frag(c+2) into the slot just consumed
            if (tile < 7 || ks < 6) {
                const int ntile = (ks >= 6) ? tile + 1 : tile;
                const int nks   = (ks + 2) & 7;
#pragma unroll
                for (int cf = 0; cf < 2; ++cf)
                    bb[cur][cf] = *reinterpret_cast<const bf16x8*>(
                        bp + (size_t)ntile * 65536 + cf * 4096 + nks * 512);
            }
        }
        // ---- per-tile epilogue: threshold select, packed into LDS cbuf ----
        const int Jt = Jbase + tile * 256;
        float sqc[2];
#pragma unroll
        for (int cf = 0; cf < 2; ++cf) sqc[cf] = sq[Jt + gcol + cf * 16 + l15];
#pragma unroll
        for (int mf = 0; mf < 4; ++mf)
#pragma unroll
            for (int cf = 0; cf < 2; ++cf)
#pragma unroll
                for (int r = 0; r < 4; ++r) {
                    const int row = mf * 16 + lg * 4 + r;
                    const float tt = Ts[row];
                    const float key = sqi_s[row] + sqc[cf] - 2.f * acc[mf][cf][r];
                    if (key < tt) {
                        const int kq2 = min((int)((tt - key) * 4096.f), 524287);
                        const uint val = ((uint)max(kq2, 0) << 13) |
                                         (uint)(Jt + gcol + cf * 16 + l15);
                        const int pos = atomicAdd(&cnt[row], 1);
                        if (pos < LCAP) cbuf[row][pos] = (int)val;
                    }
                }
    }
    __syncthreads();
    if (tid < 64) {
        const int local = cnt[tid];
        const int n = min(local, LCAP);
        const int add = (local > LCAP) ? (n + (1 << 20)) : n;   // poison on overflow
        base_s[tid] = atomicAdd(&cnt_g[row0 + tid], add);
        n_s[tid] = n;
    }
    __syncthreads();
    for (int s = tid; s < 64 * LCAP; s += 512) {
        const int r = s / LCAP, k2 = s - r * LCAP;
        if (k2 < n_s[r]) {
            const int b = base_s[r] + k2;
            if (b < CAP) cand[(size_t)(row0 + r) * CAP + b] = cbuf[r][k2];
        }
    }
}

// ---------------- K2b: parallel bad-row scan + repair (expected none) ----------------
__global__ void fallback_kernel(const float* __restrict__ feats, const float* __restrict__ sq,
                                int* __restrict__ cand, int* __restrict__ cnt_g) {
    __shared__ float fi_s[DIM];
    __shared__ float keys[NPTS];
    __shared__ float rkey[4];
    __shared__ int   rid[4];
    __shared__ int   badlist[256];
    __shared__ int   nbad_s;
    const int t = threadIdx.x;
    if (t == 0) nbad_s = 0;
    __syncthreads();
    {
        const int myrow = blockIdx.x * 256 + t;
        const int v = cnt_g[myrow];
        if (v < NSLOT || v > CAP) badlist[atomicAdd(&nbad_s, 1)] = myrow;
    }
    __syncthreads();
    const int nb = nbad_s;
    for (int bi = 0; bi < nb; ++bi) {
        const int row = badlist[bi];
        fi_s[t] = feats[(size_t)row * DIM + t];
        __syncthreads();
        const float sqi = sq[row];
        for (int p = 0; p < NPTS / 256; ++p) {
            const int jj = p * 256 + t;
            const float* fj = feats + (size_t)jj * DIM;
            float d = 0.f;
            for (int dq = 0; dq < DIM / 4; ++dq) {
                const float4 b4 = *reinterpret_cast<const float4*>(fj + dq * 4);
                const float4 a4 = *reinterpret_cast<const float4*>(&fi_s[dq * 4]);
                d = fmaf(a4.x, b4.x, fmaf(a4.y, b4.y, fmaf(a4.z, b4.z, fmaf(a4.w, b4.w, d))));
            }
            keys[jj] = sqi + sq[jj] - 2.f * d;
        }
        __syncthreads();
        for (int r = 0; r < 64; ++r) {
            float bk = INFINITY; int bj = 0x7fffffff;
            for (int p = 0; p < NPTS / 256; ++p) {
                const int jj = p * 256 + t;
                const float kv = keys[jj];
                if (kv < bk || (kv == bk && jj < bj)) { bk = kv; bj = jj; }
            }
#pragma unroll
            for (int off = 1; off <= 32; off <<= 1) {
                const float ok = __shfl_xor(bk, off, 64);
                const int   oj = __shfl_xor(bj, off, 64);
                if (ok < bk || (ok == bk && oj < bj)) { bk = ok; bj = oj; }
            }
            if ((t & 63) == 0) { rkey[t >> 6] = bk; rid[t >> 6] = bj; }
            __syncthreads();
            float fk = rkey[0]; int fj2 = rid[0];
#pragma unroll
            for (int q = 1; q < 4; ++q)
                if (rkey[q] < fk || (rkey[q] == fk && rid[q] < fj2)) { fk = rkey[q]; fj2 = rid[q]; }
            if (t == 0) {   // rank-ordered packed key (idx in low 13 bits)
                cand[(size_t)row * CAP + r] = (int)(((uint)(524287 - r) << 13) | (uint)fj2);
                keys[fj2] = INFINITY;
            }
            __syncthreads();
        }
        if (t == 0) cnt_g[row] = 64;
        __syncthreads();
    }
}

// ---------------- K3: refine v4 (2 lanes per candidate in the dot phase) ----------------
__global__ __launch_bounds__(256) void refine_kernel(
    const float* __restrict__ feats, const double* __restrict__ sqd,
    const int* __restrict__ cand, const int* __restrict__ cnt_g,
    int* __restrict__ fidx, float* __restrict__ fscr) {
    __shared__ float fi_s[4][DIM];
    __shared__ int   sel_s[4][RSEL];
    const int w = threadIdx.x >> 6, l = threadIdx.x & 63;
    const int i = blockIdx.x * 4 + w;
    *reinterpret_cast<float4*>(&fi_s[w][l * 4]) =
        *reinterpret_cast<const float4*>(feats + (size_t)i * DIM + l * 4);
    __syncthreads();                     // only barrier; waves diverge after
    const int nc   = min(cnt_g[i], CAP);
    const int want = min(nc, RSEL);
    const int* crow = cand + (size_t)i * CAP;
    uint pk[4]; bool act[4];
#pragma unroll
    for (int b = 0; b < 4; ++b) {
        const int c = b * 64 + l;
        act[b] = (c < nc);
        pk[b]  = act[b] ? (uint)crow[c] : 0u;
    }
    // (1) bisect: largest T with count(act && pk >= T) >= want (64-bit midpoint)
    uint lo = 0u, hi = 0xffffffffu;
    while (lo < hi) {
        const uint mid = (uint)(((ull)lo + (ull)hi + 1ULL) >> 1);
        int c = 0;
#pragma unroll
        for (int b = 0; b < 4; ++b) c += __popcll(__ballot(act[b] && pk[b] >= mid));
        if (c >= want) lo = mid; else hi = mid - 1u;
    }
    // (2) compact selected j-indices to sel_s[w][0..want)
    {
        int base = 0;
#pragma unroll
        for (int b = 0; b < 4; ++b) {
            const bool s = act[b] && pk[b] >= lo;
            const ull bal = __ballot(s);
            const int pos = base + __popcll(bal & ((1ULL << l) - 1ULL));
            if (s && pos < RSEL) sel_s[w][pos] = (int)(pk[b] & 8191u);
            base += __popcll(bal);
        }
    }
    // (3) fp64 dot: 2 lanes per candidate (lane pair l, l^1), 128 dims each
    const int  cidx = l >> 1, half = l & 1;
    const bool mine = (cidx < want);
    const int  j    = mine ? sel_s[w][cidx] : i;
    double dot0 = 0.0, dot1 = 0.0;
    if (mine) {
        const float* fj = feats + (size_t)j * DIM + half * 128;
        const float* fi = &fi_s[w][half * 128];
#pragma unroll 8
        for (int dq = 0; dq < 16; ++dq) {
            const float4 a0 = *reinterpret_cast<const float4*>(fi + dq * 8);
            const float4 a1 = *reinterpret_cast<const float4*>(fi + dq * 8 + 4);
            const float4 b0 = *reinterpret_cast<const float4*>(fj + dq * 8);
            const float4 b1 = *reinterpret_cast<const float4*>(fj + dq * 8 + 4);
            dot0 += (double)a0.x * b0.x + (double)a0.y * b0.y +
                    (double)a0.z * b0.z + (double)a0.w * b0.w;
            dot1 += (double)a1.x * b1.x + (double)a1.y * b1.y +
                    (double)a1.z * b1.z + (double)a1.w * b1.w;
        }
    }
    double dot = dot0 + dot1;
    dot += __shfl_xor(dot, 1, 64);       // both lanes of the pair hold full dot
    const double dd = sqd[i] + sqd[j] - 2.0 * dot;   // the np-reference formula
    // (4) 17-smallest by composite key (dd bits | idx); keys live on even lanes
    const ull key = (mine && half == 0)
                        ? ((ull)(__double_as_longlong(fmax(dd, 0.0)) & ~8191LL) | (ull)(uint)j)
                        : ~0ULL;
    ull klo = 0ULL, khi = 0x4330000000000000ULL;
    while (klo < khi) {
        const ull mid = klo + ((khi - klo) >> 1);
        const int c = __popcll(__ballot(key <= mid));
        if (c >= NSLOT) khi = mid; else klo = mid + 1ULL;
    }
    const bool s2 = (key <= khi);
    const ull bal = __ballot(s2);
    const int pos = __popcll(bal & ((1ULL << l) - 1ULL));
    if (s2 && pos < NSLOT) {
        fidx[(size_t)i * NSLOT + pos] = j;
        fscr[(size_t)i * NSLOT + pos] = (float)dot;
    }
}

// ---------------- K4: mutual mask + sparse softmax + mix + normalize ----------------
__global__ void fcm_out_kernel(const float* __restrict__ feats,
                               const int* __restrict__ knn_idx,
                               const float* __restrict__ knn_scr,
                               float* __restrict__ out) {
    const int w    = threadIdx.x >> 6;
    const int lane = threadIdx.x & 63;
    const int i    = blockIdx.x * 4 + w;

    int jt = -1; float st = 0.f; bool valid = false;
    if (lane < NSLOT) {
        jt = knn_idx[(size_t)i * NSLOT + lane];
        st = knn_scr[(size_t)i * NSLOT + lane];
        if (jt != i) {
            const int* nb = knn_idx + (size_t)jt * NSLOT;
#pragma unroll
            for (int s = 0; s < NSLOT; ++s) valid |= (nb[s] == i);
        }
    }
    float val = valid ? st : -INFINITY;
#pragma unroll
    for (int off = 32; off > 0; off >>= 1) val = fmaxf(val, __shfl_xor(val, off, 64));
    const float m  = fmaxf(1.0f, val);
    const float wt = valid ? expf(st - m) : 0.f;
    float ws = wt;
#pragma unroll
    for (int off = 32; off > 0; off >>= 1) ws += __shfl_xor(ws, off, 64);
    const float wdiag = expf(1.0f - m);
    const float inv   = 1.0f / (ws + wdiag);

    const float4 fi = *reinterpret_cast<const float4*>(feats + (size_t)i * DIM + lane * 4);
    float ax = fi.x * wdiag, ay = fi.y * wdiag, az = fi.z * wdiag, aw = fi.w * wdiag;
    for (int t = 0; t < NSLOT; ++t) {
        const float wtt = __shfl(wt, t, 64);
        const int   jj  = __shfl(jt, t, 64);
        if (wtt > 0.f) {
            const float4 fj = *reinterpret_cast<const float4*>(feats + (size_t)jj * DIM + lane * 4);
            ax = fmaf(wtt, fj.x, ax); ay = fmaf(wtt, fj.y, ay);
            az = fmaf(wtt, fj.z, az); aw = fmaf(wtt, fj.w, aw);
        }
    }
    const float ox = fmaf(ax, inv, fi.x), oy = fmaf(ay, inv, fi.y);
    const float oz = fmaf(az, inv, fi.z), ow = fmaf(aw, inv, fi.w);
    float nn = ox * ox + oy * oy + oz * oz + ow * ow;
#pragma unroll
    for (int off = 32; off > 0; off >>= 1) nn += __shfl_xor(nn, off, 64);
    const float scl = 1.0f / fmaxf(sqrtf(nn), 1e-12f);
    float4 o; o.x = ox * scl; o.y = oy * scl; o.z = oz * scl; o.w = ow * scl;
    *reinterpret_cast<float4*>(out + (size_t)i * DIM + lane * 4) = o;
}

extern "C" void kernel_launch(void* const* d_in, const int* in_sizes, int n_in,
                              void* d_out, int out_size, void* d_ws, size_t ws_size,
                              hipStream_t stream) {
    (void)in_sizes; (void)n_in; (void)out_size; (void)ws_size;
    const float* feats = (const float*)d_in[0];
    float* out = (float*)d_out;
    char* ws = (char*)d_ws;
    size_t off = 0;
    float*  sq    = (float*) (ws + off); off += NPTS * 4;                 // 32 KB
    double* sqd   = (double*)(ws + off); off += NPTS * 8;                 // 64 KB
    float*  musig = (float*) (ws + off); off += 128;
    ushort* fbp   = (ushort*)(ws + off); off += (size_t)NPTS * DIM * 2;   // 4 MB packed
    int*    cand  = (int*)   (ws + off); off += (size_t)NPTS * CAP * 4;   // 8 MB
    int*    cnt_g = (int*)   (ws + off); off += NPTS * 4;
    int*    fidx  = (int*)   (ws + off); off += NPTS * NSLOT * 4;
    float*  fscr  = (float*) (ws + off); off += NPTS * NSLOT * 4;

    pack_kernel<<<NPTS / 32, 128, 0, stream>>>(feats, fbp, sq, sqd, cnt_g);
    stats_kernel<<<1, 1024, 0, stream>>>(sq, musig);
    gemm_select_kernel<<<(NPTS / 64) * 4, 512, 0, stream>>>(fbp, sq, musig, cand, cnt_g);
    fallback_kernel<<<NPTS / 256, 256, 0, stream>>>(feats, sq, cand, cnt_g);
    refine_kernel<<<NPTS / 4, 256, 0, stream>>>(feats, sqd, cand, cnt_g, fidx, fscr);
    fcm_out_kernel<<<NPTS / 4, 256, 0, stream>>>(feats, fidx, fscr, out);
}